// Round 5
// baseline (282.879 us; speedup 1.0000x reference)
//
#include <hip/hip_runtime.h>

typedef __bf16 bf16;
typedef __bf16 bf16x4 __attribute__((ext_vector_type(4)));
typedef __bf16 bf16x8 __attribute__((ext_vector_type(8)));
typedef float f32x4 __attribute__((ext_vector_type(4)));

#define DIM   2048
#define BQ    128
#define KVL   4096
#define KVT   4224   // KV_LEN + Q_LEN
#define SCALE 0.022097086912079608f  // 1/sqrt(2048)

// Swizzled element offset inside a [ROWS][64]-bf16 LDS tile (128B rows).
__device__ __forceinline__ int swz(int row, int col) {
  return row * 64 + (col ^ ((row & 7) << 3));
}

// ---- async 16B global->LDS (wave-uniform LDS base + lane*16) ----
__device__ __forceinline__ void gload16(const bf16* g, bf16* l) {
  __builtin_amdgcn_global_load_lds(
      (const __attribute__((address_space(1))) void*)g,
      (__attribute__((address_space(3))) void*)l, 16, 0, 0);
}

// Stage a [R][64] bf16 tile from row-major src (ld elems) into LDS such that
// reads via swz() are correct: LINEAR LDS dest + XOR-pre-swizzled global
// source (rule #21: source perm == read perm, both XOR by row&7 at 16B chunks).
// One gload16 moves 8 rows (64 lanes x 16B). NW waves split the rows.
template<int R, int NW>
__device__ __forceinline__ void gstage(const bf16* __restrict__ src, int ld,
                                       bf16* dst, int wid, int lane) {
  constexpr int OPS = R / (8 * NW);
  const int rsub = lane >> 3;                         // 0..7 row within 8-row group
  const int schunk = (lane & 7) ^ (rsub & 7);         // pre-swizzled source chunk
  #pragma unroll
  for (int j = 0; j < OPS; ++j) {
    const int row0 = wid * (R / NW) + j * 8;          // multiple of 8
    gload16(src + (size_t)(row0 + rsub) * ld + schunk * 8, dst + row0 * 64);
  }
}

// ---------- register prefetch of a [64][64] tile from f32 OR bf16 src ----------
struct PU64 {
  float4 v[4];
  int r0, c;
  __device__ __forceinline__ void init(int tid) { r0 = tid >> 4; c = (tid & 15) * 4; }
  __device__ __forceinline__ void loadF(const float* __restrict__ src, int ld) {
    #pragma unroll
    for (int j = 0; j < 4; ++j)
      v[j] = *reinterpret_cast<const float4*>(src + (size_t)(j * 16 + r0) * ld + c);
  }
  __device__ __forceinline__ void loadB(const bf16* __restrict__ src, int ld) {
    #pragma unroll
    for (int j = 0; j < 4; ++j) {
      bf16x4 t = *reinterpret_cast<const bf16x4*>(src + (size_t)(j * 16 + r0) * ld + c);
      v[j].x = (float)t[0]; v[j].y = (float)t[1]; v[j].z = (float)t[2]; v[j].w = (float)t[3];
    }
  }
  __device__ __forceinline__ void write(bf16* dst) {
    #pragma unroll
    for (int j = 0; j < 4; ++j) {
      bf16x4 b;
      b[0] = (bf16)v[j].x; b[1] = (bf16)v[j].y; b[2] = (bf16)v[j].z; b[3] = (bf16)v[j].w;
      *reinterpret_cast<bf16x4*>(dst + swz(j * 16 + r0, c)) = b;
    }
  }
};

// ---------- transpose prefetch: V[64k][DIM] slice -> VT[64n][64k] ----------
struct PVT {
  float v[16];
  int vn, vk0;
  __device__ __forceinline__ void init(int tid) { vn = tid & 63; vk0 = (tid >> 6) * 16; }
  __device__ __forceinline__ void loadF(const float* __restrict__ src) {
    #pragma unroll
    for (int i = 0; i < 16; ++i) v[i] = src[(size_t)(vk0 + i) * DIM + vn];
  }
  __device__ __forceinline__ void loadB(const bf16* __restrict__ src) {
    #pragma unroll
    for (int i = 0; i < 16; ++i) v[i] = (float)src[(size_t)(vk0 + i) * DIM + vn];
  }
  __device__ __forceinline__ void write(bf16* dst) {
    #pragma unroll
    for (int j = 0; j < 4; ++j) {
      bf16x4 t;
      #pragma unroll
      for (int i = 0; i < 4; ++i) t[i] = (bf16)v[4 * j + i];
      *reinterpret_cast<bf16x4*>(dst + swz(vn, vk0 + 4 * j)) = t;
    }
  }
};

// ---- wave tile: MF x NF fragments of 16x16, K-depth 64 (2 mfma k-steps) ----
template<int MF, int NF>
__device__ __forceinline__ void mma_tile(const bf16* As, const bf16* Bs,
                                         f32x4 (&acc)[MF][NF], int l, int wm, int wn) {
  const int ar = l & 15;
  const int ak = (l >> 4) * 8;
  bf16x8 a[MF][2], b[NF][2];
  #pragma unroll
  for (int mi = 0; mi < MF; ++mi)
    #pragma unroll
    for (int kk = 0; kk < 2; ++kk)
      a[mi][kk] = *reinterpret_cast<const bf16x8*>(As + swz(wm + mi * 16 + ar, kk * 32 + ak));
  #pragma unroll
  for (int ni = 0; ni < NF; ++ni)
    #pragma unroll
    for (int kk = 0; kk < 2; ++kk)
      b[ni][kk] = *reinterpret_cast<const bf16x8*>(Bs + swz(wn + ni * 16 + ar, kk * 32 + ak));
  #pragma unroll
  for (int kk = 0; kk < 2; ++kk)
    #pragma unroll
    for (int mi = 0; mi < MF; ++mi)
      #pragma unroll
      for (int ni = 0; ni < NF; ++ni)
        acc[mi][ni] = __builtin_amdgcn_mfma_f32_16x16x32_bf16(
            a[mi][kk], b[ni][kk], acc[mi][ni], 0, 0, 0);
}

// ============ Kernel 0: f32 -> bf16 conversion (x + 4 weights) ============
__global__ __launch_bounds__(256) void k_cvt(const float* __restrict__ x,
    const float* __restrict__ wq, const float* __restrict__ wk,
    const float* __restrict__ wv, const float* __restrict__ wo,
    bf16* __restrict__ xb, bf16* __restrict__ wb) {
  const int seg = blockIdx.y;
  const float* src; bf16* dst; int n; float sc = 1.0f;
  if (seg == 0)      { src = x;  dst = xb;            n = 1024 * DIM; }
  else if (seg == 1) { src = wq; dst = wb;            n = DIM * DIM; sc = SCALE; }
  else if (seg == 2) { src = wk; dst = wb + 1 * DIM * DIM; n = DIM * DIM; }
  else if (seg == 3) { src = wv; dst = wb + 2 * DIM * DIM; n = DIM * DIM; }
  else               { src = wo; dst = wb + 3 * DIM * DIM; n = DIM * DIM; }
  const int i0 = (blockIdx.x * 256 + threadIdx.x) * 8;
  if (i0 >= n) return;
  #pragma unroll
  for (int h = 0; h < 2; ++h) {
    float4 v = *reinterpret_cast<const float4*>(src + i0 + 4 * h);
    bf16x4 b;
    b[0] = (bf16)(v.x * sc); b[1] = (bf16)(v.y * sc);
    b[2] = (bf16)(v.z * sc); b[3] = (bf16)(v.w * sc);
    *reinterpret_cast<bf16x4*>(dst + i0 + 4 * h) = b;
  }
}

// ============ Kernel A: q/k/v projections (xb @ wb^T), 128x64 tiles ============
// grid (96, 8). Both tiles staged by global_load_lds (zero staging VALU).
__global__ __launch_bounds__(256) void k_qkv(const bf16* __restrict__ xb,
    const bf16* __restrict__ wb,
    bf16* __restrict__ qb, bf16* __restrict__ kb, bf16* __restrict__ vb) {
  __shared__ bf16 As[2][128 * 64];
  __shared__ bf16 Bs[2][64 * 64];
  const int nt = blockIdx.x;
  const int w  = nt >> 5;
  const int col0 = (nt & 31) * 64;
  bf16* __restrict__ O = (w == 0) ? qb : (w == 1) ? kb : vb;
  const int m0 = blockIdx.y * 128;
  const int tid = threadIdx.x, l = tid & 63, wid = tid >> 6;
  const int wm = (wid >> 1) * 64, wn = (wid & 1) * 32;
  const bf16* Ap = xb + (size_t)m0 * DIM;
  const bf16* Bp = wb + (size_t)nt * 64 * DIM;
  f32x4 acc[4][2] = {};
  gstage<128, 4>(Ap, DIM, As[0], wid, l);
  gstage<64, 4>(Bp, DIM, Bs[0], wid, l);
  __syncthreads();
  constexpr int NT = DIM / 64;
  for (int kt = 0; kt < NT; ++kt) {
    if (kt + 1 < NT) {
      gstage<128, 4>(Ap + (kt + 1) * 64, DIM, As[(kt + 1) & 1], wid, l);
      gstage<64, 4>(Bp + (kt + 1) * 64, DIM, Bs[(kt + 1) & 1], wid, l);
    }
    mma_tile<4, 2>(As[kt & 1], Bs[kt & 1], acc, l, wm, wn);
    __syncthreads();
  }
  const int rr = (l >> 4) * 4, cc = l & 15;
  #pragma unroll
  for (int mi = 0; mi < 4; ++mi)
    #pragma unroll
    for (int ni = 0; ni < 2; ++ni)
      #pragma unroll
      for (int r = 0; r < 4; ++r)
        O[(size_t)(m0 + wm + mi * 16 + rr + r) * DIM + col0 + wn + ni * 16 + cc] =
            (bf16)acc[mi][ni][r];
}

// ============ Kernel B: scores = q @ k^T (q pre-scaled), 128x64 tiles ============
// grid (66, 8). A (q, bf16) via global_load_lds; B (k_cache f32 / k_new bf16) reg-staged.
__global__ __launch_bounds__(256) void k_scores(const bf16* __restrict__ qb,
    const bf16* __restrict__ kb, const float* __restrict__ kcache,
    float* __restrict__ scores) {
  __shared__ bf16 As[2][128 * 64];
  __shared__ bf16 Bs[2][64 * 64];
  const int nt = blockIdx.x;
  const int b  = blockIdx.y;
  const int tid = threadIdx.x, l = tid & 63, wid = tid >> 6;
  const int wm = (wid >> 1) * 64, wn = (wid & 1) * 32;
  const bf16* Q = qb + (size_t)b * BQ * DIM;
  const bool useCache = (nt < 64);
  const float* Bf = kcache + ((size_t)b * KVL + nt * 64) * DIM;
  const bf16*  Bb = kb + ((size_t)b * BQ + (nt - 64) * 64) * DIM;
  PU64 pu; pu.init(tid);
  f32x4 acc[4][2] = {};
  gstage<128, 4>(Q, DIM, As[0], wid, l);
  if (useCache) pu.loadF(Bf, DIM); else pu.loadB(Bb, DIM);
  pu.write(Bs[0]);
  __syncthreads();
  constexpr int NT = DIM / 64;
  for (int kt = 0; kt < NT; ++kt) {
    if (kt + 1 < NT) {
      gstage<128, 4>(Q + (kt + 1) * 64, DIM, As[(kt + 1) & 1], wid, l);
      if (useCache) pu.loadF(Bf + (kt + 1) * 64, DIM); else pu.loadB(Bb + (kt + 1) * 64, DIM);
    }
    mma_tile<4, 2>(As[kt & 1], Bs[kt & 1], acc, l, wm, wn);
    if (kt + 1 < NT) pu.write(Bs[(kt + 1) & 1]);
    __syncthreads();
  }
  const int rr = (l >> 4) * 4, cc = l & 15;
  #pragma unroll
  for (int mi = 0; mi < 4; ++mi)
    #pragma unroll
    for (int ni = 0; ni < 2; ++ni)
      #pragma unroll
      for (int r = 0; r < 4; ++r)
        scores[((size_t)b * BQ + wm + mi * 16 + rr + r) * KVT + nt * 64 + wn + ni * 16 + cc] =
            acc[mi][ni][r];
}

// ================= Kernel C: row softmax -> bf16 attn =================
__global__ __launch_bounds__(256) void k_softmax(const float* __restrict__ scores,
                                                 bf16* __restrict__ attn) {
  __shared__ float s[KVT];
  __shared__ float red[8];
  const int row = blockIdx.x;
  const int tid = threadIdx.x;
  const size_t base = (size_t)row * KVT;
  float lm = -1e30f;
  for (int i = tid; i < KVT; i += 256) {
    float v = scores[base + i];
    s[i] = v;
    lm = fmaxf(lm, v);
  }
  #pragma unroll
  for (int off = 32; off >= 1; off >>= 1) lm = fmaxf(lm, __shfl_xor(lm, off, 64));
  if ((tid & 63) == 0) red[tid >> 6] = lm;
  __syncthreads();
  const float m = fmaxf(fmaxf(red[0], red[1]), fmaxf(red[2], red[3]));
  float ls = 0.f;
  for (int i = tid; i < KVT; i += 256) {
    float e = __expf(s[i] - m);
    s[i] = e;
    ls += e;
  }
  #pragma unroll
  for (int off = 32; off >= 1; off >>= 1) ls += __shfl_xor(ls, off, 64);
  if ((tid & 63) == 0) red[4 + (tid >> 6)] = ls;
  __syncthreads();
  const float inv = 1.f / (red[4] + red[5] + red[6] + red[7]);
  for (int i = tid; i < KVT; i += 256) attn[base + i] = (bf16)(s[i] * inv);
}

// ============ Kernel D: partial out = attn @ V over a KV chunk ============
// grid (32, 8, 2). A (attn bf16) via global_load_lds; V reg-transpose-staged.
__global__ __launch_bounds__(256) void k_pv(const bf16* __restrict__ attn,
    const float* __restrict__ vcache, const bf16* __restrict__ vb,
    float* __restrict__ pp) {
  __shared__ bf16 As[2][128 * 64];
  __shared__ bf16 VT[2][64 * 64];
  const int n0 = blockIdx.x * 64;
  const int b  = blockIdx.y;
  const int c  = blockIdx.z;
  const int tid = threadIdx.x, l = tid & 63, wid = tid >> 6;
  const int wm = (wid >> 1) * 64, wn = (wid & 1) * 32;
  const bf16* Ap = attn + (size_t)b * BQ * KVT + c * 2112;
  PVT pv; pv.init(tid);
  f32x4 acc[4][2] = {};
  auto loadV = [&](int lk) {
    const int grow = c * 2112 + lk * 64;
    if (grow < KVL) pv.loadF(vcache + ((size_t)b * KVL + grow) * DIM + n0);
    else            pv.loadB(vb + ((size_t)b * BQ + (grow - KVL)) * DIM + n0);
  };
  gstage<128, 4>(Ap, KVT, As[0], wid, l);
  loadV(0); pv.write(VT[0]);
  __syncthreads();
  constexpr int NT = 33;
  for (int kt = 0; kt < NT; ++kt) {
    if (kt + 1 < NT) {
      gstage<128, 4>(Ap + (kt + 1) * 64, KVT, As[(kt + 1) & 1], wid, l);
      loadV(kt + 1);
    }
    mma_tile<4, 2>(As[kt & 1], VT[kt & 1], acc, l, wm, wn);
    if (kt + 1 < NT) pv.write(VT[(kt + 1) & 1]);
    __syncthreads();
  }
  float* P = pp + (size_t)c * 1024 * DIM;
  const int rr = (l >> 4) * 4, cc = l & 15;
  #pragma unroll
  for (int mi = 0; mi < 4; ++mi)
    #pragma unroll
    for (int ni = 0; ni < 2; ++ni)
      #pragma unroll
      for (int r = 0; r < 4; ++r)
        P[((size_t)b * BQ + wm + mi * 16 + rr + r) * DIM + n0 + wn + ni * 16 + cc] =
            acc[mi][ni][r];
}

// ============ combine: obuf = bf16(pp0 + pp1) ============
__global__ __launch_bounds__(256) void k_pvcomb(const float* __restrict__ pp,
                                                bf16* __restrict__ ob) {
  const int i0 = (blockIdx.x * 256 + threadIdx.x) * 4;
  float4 a = *reinterpret_cast<const float4*>(pp + i0);
  float4 b = *reinterpret_cast<const float4*>(pp + 1024 * DIM + i0);
  bf16x4 o;
  o[0] = (bf16)(a.x + b.x); o[1] = (bf16)(a.y + b.y);
  o[2] = (bf16)(a.z + b.z); o[3] = (bf16)(a.w + b.w);
  *reinterpret_cast<bf16x4*>(ob + i0) = o;
}

// ============ Kernel E: final = obuf @ wo'^T (fp32 out), 128x64 tiles ============
// grid (32, 8). Both tiles bf16 via global_load_lds; fp32 result straight to out.
__global__ __launch_bounds__(256) void k_oproj(const bf16* __restrict__ ob,
    const bf16* __restrict__ wob, float* __restrict__ out) {
  __shared__ bf16 As[2][128 * 64];
  __shared__ bf16 Bs[2][64 * 64];
  const int n0 = blockIdx.x * 64;
  const int m0 = blockIdx.y * 128;
  const int tid = threadIdx.x, l = tid & 63, wid = tid >> 6;
  const int wm = (wid >> 1) * 64, wn = (wid & 1) * 32;
  const bf16* Ap = ob  + (size_t)m0 * DIM;
  const bf16* Bp = wob + (size_t)n0 * DIM;
  f32x4 acc[4][2] = {};
  gstage<128, 4>(Ap, DIM, As[0], wid, l);
  gstage<64, 4>(Bp, DIM, Bs[0], wid, l);
  __syncthreads();
  constexpr int NT = DIM / 64;
  for (int kt = 0; kt < NT; ++kt) {
    if (kt + 1 < NT) {
      gstage<128, 4>(Ap + (kt + 1) * 64, DIM, As[(kt + 1) & 1], wid, l);
      gstage<64, 4>(Bp + (kt + 1) * 64, DIM, Bs[(kt + 1) & 1], wid, l);
    }
    mma_tile<4, 2>(As[kt & 1], Bs[kt & 1], acc, l, wm, wn);
    __syncthreads();
  }
  const int rr = (l >> 4) * 4, cc = l & 15;
  #pragma unroll
  for (int mi = 0; mi < 4; ++mi)
    #pragma unroll
    for (int ni = 0; ni < 2; ++ni)
      #pragma unroll
      for (int r = 0; r < 4; ++r)
        out[(size_t)(m0 + wm + mi * 16 + rr + r) * DIM + n0 + wn + ni * 16 + cc] =
            acc[mi][ni][r];
}

extern "C" void kernel_launch(void* const* d_in, const int* in_sizes, int n_in,
                              void* d_out, int out_size, void* d_ws, size_t ws_size,
                              hipStream_t stream) {
  const float* x      = (const float*)d_in[0];
  // d_in[1] = mask (unused by the reference forward)
  const float* kcache = (const float*)d_in[2];
  const float* vcache = (const float*)d_in[3];
  const float* wq     = (const float*)d_in[4];
  const float* wk     = (const float*)d_in[5];
  const float* wv     = (const float*)d_in[6];
  const float* wo     = (const float*)d_in[7];
  float* out = (float*)d_out;

  char* ws = (char*)d_ws;                       // ws ~1 GB
  bf16*  xb     = (bf16*)(ws + 0);              //  4.19 MB [1024][2048]
  bf16*  wb     = (bf16*)(ws + 4194304);        // 33.55 MB [4*2048][2048]
  bf16*  qb     = (bf16*)(ws + 37748736);       //  4.19 MB
  bf16*  kb     = (bf16*)(ws + 41943040);       //  4.19 MB
  bf16*  vb     = (bf16*)(ws + 46137344);       //  4.19 MB
  float* scores = (float*)(ws + 50331648);      // 17.30 MB [1024][4224]
  bf16*  attnb  = (bf16*)(ws + 67633152);       //  8.65 MB
  bf16*  obuf   = (bf16*)(ws + 76283904);       //  4.19 MB
  float* pp     = (float*)(ws + 80478208);      // 16.78 MB (2x f32 partials)
  bf16*  wob    = wb + (size_t)3 * DIM * DIM;

  k_cvt<<<dim3(2048, 5), 256, 0, stream>>>(x, wq, wk, wv, wo, xb, wb);
  k_qkv<<<dim3(96, 8), 256, 0, stream>>>(xb, wb, qb, kb, vb);
  k_scores<<<dim3(66, 8), 256, 0, stream>>>(qb, kb, kcache, scores);
  k_softmax<<<dim3(1024), 256, 0, stream>>>(scores, attnb);
  k_pv<<<dim3(32, 8, 2), 256, 0, stream>>>(attnb, vcache, vb, pp);
  k_pvcomb<<<dim3(2048), 256, 0, stream>>>(pp, obuf);
  k_oproj<<<dim3(32, 8), 256, 0, stream>>>(obuf, wob, out);
}

// Round 6
// 257.541 us; speedup vs baseline: 1.0984x; 1.0984x over previous
//
#include <hip/hip_runtime.h>

typedef __bf16 bf16;
typedef __bf16 bf16x4 __attribute__((ext_vector_type(4)));
typedef __bf16 bf16x8 __attribute__((ext_vector_type(8)));
typedef float f32x4 __attribute__((ext_vector_type(4)));

#define DIM   2048
#define BQ    128
#define KVL   4096
#define KVT   4224   // KV_LEN + Q_LEN
#define SCALE 0.022097086912079608f  // 1/sqrt(2048)

// Swizzled element offset inside a [ROWS][64]-bf16 LDS tile (128B rows).
__device__ __forceinline__ int swz(int row, int col) {
  return row * 64 + (col ^ ((row & 7) << 3));
}

// ---------- register staging of a [R][64] bf16 tile, NTHR threads ----------
template<int R, int NTHR>
struct PBg {
  static constexpr int N8 = R * 64 / (NTHR * 8);   // bf16x8 per thread
  bf16x8 v[N8];
  __device__ __forceinline__ void load(const bf16* __restrict__ src, int ld, int tid) {
    const int r0 = tid >> 3, c = (tid & 7) * 8;
    #pragma unroll
    for (int j = 0; j < N8; ++j)
      v[j] = *reinterpret_cast<const bf16x8*>(src + (size_t)(j * (NTHR / 8) + r0) * ld + c);
  }
  __device__ __forceinline__ void write(bf16* dst, int tid) {
    const int r0 = tid >> 3, c = (tid & 7) * 8;
    #pragma unroll
    for (int j = 0; j < N8; ++j)
      *reinterpret_cast<bf16x8*>(dst + swz(j * (NTHR / 8) + r0, c)) = v[j];
  }
};

// ---------- register prefetch of a [64][64] tile from f32 OR bf16 src ----------
struct PU64 {
  float4 v[4];
  int r0, c;
  __device__ __forceinline__ void init(int tid) { r0 = tid >> 4; c = (tid & 15) * 4; }
  __device__ __forceinline__ void loadF(const float* __restrict__ src, int ld) {
    #pragma unroll
    for (int j = 0; j < 4; ++j)
      v[j] = *reinterpret_cast<const float4*>(src + (size_t)(j * 16 + r0) * ld + c);
  }
  __device__ __forceinline__ void loadB(const bf16* __restrict__ src, int ld) {
    #pragma unroll
    for (int j = 0; j < 4; ++j) {
      bf16x4 t = *reinterpret_cast<const bf16x4*>(src + (size_t)(j * 16 + r0) * ld + c);
      v[j].x = (float)t[0]; v[j].y = (float)t[1]; v[j].z = (float)t[2]; v[j].w = (float)t[3];
    }
  }
  __device__ __forceinline__ void write(bf16* dst) {
    #pragma unroll
    for (int j = 0; j < 4; ++j) {
      bf16x4 b;
      b[0] = (bf16)v[j].x; b[1] = (bf16)v[j].y; b[2] = (bf16)v[j].z; b[3] = (bf16)v[j].w;
      *reinterpret_cast<bf16x4*>(dst + swz(j * 16 + r0, c)) = b;
    }
  }
};

// ---------- transpose prefetch: V[64k][DIM] slice -> VT[64n][64k] ----------
struct PVT {
  float v[16];
  int vn, vk0;
  __device__ __forceinline__ void init(int tid) { vn = tid & 63; vk0 = (tid >> 6) * 16; }
  __device__ __forceinline__ void loadF(const float* __restrict__ src) {
    #pragma unroll
    for (int i = 0; i < 16; ++i) v[i] = src[(size_t)(vk0 + i) * DIM + vn];
  }
  __device__ __forceinline__ void loadB(const bf16* __restrict__ src) {
    #pragma unroll
    for (int i = 0; i < 16; ++i) v[i] = (float)src[(size_t)(vk0 + i) * DIM + vn];
  }
  __device__ __forceinline__ void write(bf16* dst) {
    #pragma unroll
    for (int j = 0; j < 4; ++j) {
      bf16x4 t;
      #pragma unroll
      for (int i = 0; i < 4; ++i) t[i] = (bf16)v[4 * j + i];
      *reinterpret_cast<bf16x4*>(dst + swz(vn, vk0 + 4 * j)) = t;
    }
  }
};

// ---- wave tile: MF x NF fragments of 16x16, K-depth 64 (2 mfma k-steps) ----
template<int MF, int NF>
__device__ __forceinline__ void mma_tile(const bf16* As, const bf16* Bs,
                                         f32x4 (&acc)[MF][NF], int l, int wm, int wn) {
  const int ar = l & 15;
  const int ak = (l >> 4) * 8;
  bf16x8 a[MF][2], b[NF][2];
  #pragma unroll
  for (int mi = 0; mi < MF; ++mi)
    #pragma unroll
    for (int kk = 0; kk < 2; ++kk)
      a[mi][kk] = *reinterpret_cast<const bf16x8*>(As + swz(wm + mi * 16 + ar, kk * 32 + ak));
  #pragma unroll
  for (int ni = 0; ni < NF; ++ni)
    #pragma unroll
    for (int kk = 0; kk < 2; ++kk)
      b[ni][kk] = *reinterpret_cast<const bf16x8*>(Bs + swz(wn + ni * 16 + ar, kk * 32 + ak));
  #pragma unroll
  for (int kk = 0; kk < 2; ++kk)
    #pragma unroll
    for (int mi = 0; mi < MF; ++mi)
      #pragma unroll
      for (int ni = 0; ni < NF; ++ni)
        acc[mi][ni] = __builtin_amdgcn_mfma_f32_16x16x32_bf16(
            a[mi][kk], b[ni][kk], acc[mi][ni], 0, 0, 0);
}

// ============ Kernel 0: f32 -> bf16 conversion (x + 4 weights) ============
__global__ __launch_bounds__(256) void k_cvt(const float* __restrict__ x,
    const float* __restrict__ wq, const float* __restrict__ wk,
    const float* __restrict__ wv, const float* __restrict__ wo,
    bf16* __restrict__ xb, bf16* __restrict__ wb) {
  const int seg = blockIdx.y;
  const float* src; bf16* dst; int n; float sc = 1.0f;
  if (seg == 0)      { src = x;  dst = xb;            n = 1024 * DIM; }
  else if (seg == 1) { src = wq; dst = wb;            n = DIM * DIM; sc = SCALE; }
  else if (seg == 2) { src = wk; dst = wb + 1 * DIM * DIM; n = DIM * DIM; }
  else if (seg == 3) { src = wv; dst = wb + 2 * DIM * DIM; n = DIM * DIM; }
  else               { src = wo; dst = wb + 3 * DIM * DIM; n = DIM * DIM; }
  const int i0 = (blockIdx.x * 256 + threadIdx.x) * 8;
  if (i0 >= n) return;
  #pragma unroll
  for (int h = 0; h < 2; ++h) {
    float4 v = *reinterpret_cast<const float4*>(src + i0 + 4 * h);
    bf16x4 b;
    b[0] = (bf16)(v.x * sc); b[1] = (bf16)(v.y * sc);
    b[2] = (bf16)(v.z * sc); b[3] = (bf16)(v.w * sc);
    *reinterpret_cast<bf16x4*>(dst + i0 + 4 * h) = b;
  }
}

// ============ Kernel A: q/k/v projections (xb @ wb^T), 128x64 tiles ============
// grid (96, 8), 128 threads = 2 waves, each wave a 64x64 sub-tile (4x4 frags,
// 32 MFMA/K-step). Single-buffer LDS (24KB -> 6 blocks/CU), issue-early regs.
__global__ __launch_bounds__(128) void k_qkv(const bf16* __restrict__ xb,
    const bf16* __restrict__ wb,
    bf16* __restrict__ qb, bf16* __restrict__ kb, bf16* __restrict__ vb) {
  __shared__ bf16 As[128 * 64];
  __shared__ bf16 Bs[64 * 64];
  const int nt = blockIdx.x;
  const int w  = nt >> 5;
  const int col0 = (nt & 31) * 64;
  bf16* __restrict__ O = (w == 0) ? qb : (w == 1) ? kb : vb;
  const int m0 = blockIdx.y * 128;
  const int tid = threadIdx.x, l = tid & 63, wid = tid >> 6;
  const int wm = wid * 64;
  const bf16* Ap = xb + (size_t)m0 * DIM;
  const bf16* Bp = wb + (size_t)nt * 64 * DIM;
  PBg<128, 128> pa; PBg<64, 128> pb;
  f32x4 acc[4][4] = {};
  pa.load(Ap, DIM, tid); pb.load(Bp, DIM, tid);
  pa.write(As, tid);     pb.write(Bs, tid);
  __syncthreads();
  constexpr int NT = DIM / 64;
  for (int kt = 0; kt < NT; ++kt) {
    if (kt + 1 < NT) { pa.load(Ap + (kt + 1) * 64, DIM, tid); pb.load(Bp + (kt + 1) * 64, DIM, tid); }
    mma_tile<4, 4>(As, Bs, acc, l, wm, 0);
    __syncthreads();
    if (kt + 1 < NT) { pa.write(As, tid); pb.write(Bs, tid); }
    __syncthreads();
  }
  const int rr = (l >> 4) * 4, cc = l & 15;
  #pragma unroll
  for (int mi = 0; mi < 4; ++mi)
    #pragma unroll
    for (int ni = 0; ni < 4; ++ni)
      #pragma unroll
      for (int r = 0; r < 4; ++r)
        O[(size_t)(m0 + wm + mi * 16 + rr + r) * DIM + col0 + ni * 16 + cc] =
            (bf16)acc[mi][ni][r];
}

// ============ Kernel B: scores = q @ k^T (q pre-scaled), 128x64 tiles ============
// grid (66, 8). 256 thr / 4 waves (64x32 wave-tiles). Round-4 proven structure.
__global__ __launch_bounds__(256) void k_scores(const bf16* __restrict__ qb,
    const bf16* __restrict__ kb, const float* __restrict__ kcache,
    float* __restrict__ scores) {
  __shared__ bf16 As[2][128 * 64];
  __shared__ bf16 Bs[2][64 * 64];
  const int nt = blockIdx.x;
  const int b  = blockIdx.y;
  const int tid = threadIdx.x, l = tid & 63, wid = tid >> 6;
  const int wm = (wid >> 1) * 64, wn = (wid & 1) * 32;
  const bf16* Q = qb + (size_t)b * BQ * DIM;
  const bool useCache = (nt < 64);
  const float* Bf = kcache + ((size_t)b * KVL + nt * 64) * DIM;
  const bf16*  Bb = kb + ((size_t)b * BQ + (nt - 64) * 64) * DIM;
  PBg<128, 256> pa; PU64 pu; pu.init(tid);
  f32x4 acc[4][2] = {};
  pa.load(Q, DIM, tid);
  if (useCache) pu.loadF(Bf, DIM); else pu.loadB(Bb, DIM);
  pa.write(As[0], tid); pu.write(Bs[0]);
  int cur = 0;
  constexpr int NT = DIM / 64;
  for (int kt = 0; kt < NT; ++kt) {
    if (kt + 1 < NT) {
      pa.load(Q + (kt + 1) * 64, DIM, tid);
      if (useCache) pu.loadF(Bf + (kt + 1) * 64, DIM); else pu.loadB(Bb + (kt + 1) * 64, DIM);
    }
    __syncthreads();
    mma_tile<4, 2>(As[cur], Bs[cur], acc, l, wm, wn);
    if (kt + 1 < NT) { pa.write(As[cur ^ 1], tid); pu.write(Bs[cur ^ 1]); }
    cur ^= 1;
  }
  const int rr = (l >> 4) * 4, cc = l & 15;
  #pragma unroll
  for (int mi = 0; mi < 4; ++mi)
    #pragma unroll
    for (int ni = 0; ni < 2; ++ni)
      #pragma unroll
      for (int r = 0; r < 4; ++r)
        scores[((size_t)b * BQ + wm + mi * 16 + rr + r) * KVT + nt * 64 + wn + ni * 16 + cc] =
            acc[mi][ni][r];
}

// ================= Kernel C: row softmax -> bf16 attn =================
__global__ __launch_bounds__(256) void k_softmax(const float* __restrict__ scores,
                                                 bf16* __restrict__ attn) {
  __shared__ float s[KVT];
  __shared__ float red[8];
  const int row = blockIdx.x;
  const int tid = threadIdx.x;
  const size_t base = (size_t)row * KVT;
  float lm = -1e30f;
  for (int i = tid; i < KVT; i += 256) {
    float v = scores[base + i];
    s[i] = v;
    lm = fmaxf(lm, v);
  }
  #pragma unroll
  for (int off = 32; off >= 1; off >>= 1) lm = fmaxf(lm, __shfl_xor(lm, off, 64));
  if ((tid & 63) == 0) red[tid >> 6] = lm;
  __syncthreads();
  const float m = fmaxf(fmaxf(red[0], red[1]), fmaxf(red[2], red[3]));
  float ls = 0.f;
  for (int i = tid; i < KVT; i += 256) {
    float e = __expf(s[i] - m);
    s[i] = e;
    ls += e;
  }
  #pragma unroll
  for (int off = 32; off >= 1; off >>= 1) ls += __shfl_xor(ls, off, 64);
  if ((tid & 63) == 0) red[4 + (tid >> 6)] = ls;
  __syncthreads();
  const float inv = 1.f / (red[4] + red[5] + red[6] + red[7]);
  for (int i = tid; i < KVT; i += 256) attn[base + i] = (bf16)(s[i] * inv);
}

// ============ Kernel D: partial out = attn @ V over a KV chunk ============
// grid (32, 8, 2). Round-4 proven structure (dbuf, issue-early, 1 barrier).
__global__ __launch_bounds__(256) void k_pv(const bf16* __restrict__ attn,
    const float* __restrict__ vcache, const bf16* __restrict__ vb,
    float* __restrict__ pp) {
  __shared__ bf16 As[2][128 * 64];
  __shared__ bf16 VT[2][64 * 64];
  const int n0 = blockIdx.x * 64;
  const int b  = blockIdx.y;
  const int c  = blockIdx.z;
  const int tid = threadIdx.x, l = tid & 63, wid = tid >> 6;
  const int wm = (wid >> 1) * 64, wn = (wid & 1) * 32;
  const bf16* Ap = attn + (size_t)b * BQ * KVT + c * 2112;
  PBg<128, 256> pa; PVT pv; pv.init(tid);
  f32x4 acc[4][2] = {};
  auto loadV = [&](int lk) {
    const int grow = c * 2112 + lk * 64;
    if (grow < KVL) pv.loadF(vcache + ((size_t)b * KVL + grow) * DIM + n0);
    else            pv.loadB(vb + ((size_t)b * BQ + (grow - KVL)) * DIM + n0);
  };
  pa.load(Ap, KVT, tid); loadV(0);
  pa.write(As[0], tid);  pv.write(VT[0]);
  int cur = 0;
  constexpr int NT = 33;
  for (int kt = 0; kt < NT; ++kt) {
    if (kt + 1 < NT) { pa.load(Ap + (kt + 1) * 64, KVT, tid); loadV(kt + 1); }
    __syncthreads();
    mma_tile<4, 2>(As[cur], VT[cur], acc, l, wm, wn);
    if (kt + 1 < NT) { pa.write(As[cur ^ 1], tid); pv.write(VT[cur ^ 1]); }
    cur ^= 1;
  }
  float* P = pp + (size_t)c * 1024 * DIM;
  const int rr = (l >> 4) * 4, cc = l & 15;
  #pragma unroll
  for (int mi = 0; mi < 4; ++mi)
    #pragma unroll
    for (int ni = 0; ni < 2; ++ni)
      #pragma unroll
      for (int r = 0; r < 4; ++r)
        P[((size_t)b * BQ + wm + mi * 16 + rr + r) * DIM + n0 + wn + ni * 16 + cc] =
            acc[mi][ni][r];
}

// ============ combine: obuf = bf16(pp0 + pp1) ============
__global__ __launch_bounds__(256) void k_pvcomb(const float* __restrict__ pp,
                                                bf16* __restrict__ ob) {
  const int i0 = (blockIdx.x * 256 + threadIdx.x) * 4;
  float4 a = *reinterpret_cast<const float4*>(pp + i0);
  float4 b = *reinterpret_cast<const float4*>(pp + 1024 * DIM + i0);
  bf16x4 o;
  o[0] = (bf16)(a.x + b.x); o[1] = (bf16)(a.y + b.y);
  o[2] = (bf16)(a.z + b.z); o[3] = (bf16)(a.w + b.w);
  *reinterpret_cast<bf16x4*>(ob + i0) = o;
}

// ============ Kernel E: partial final = obuf @ wo'^T over a K half ============
// grid (32, 8, 2), 128 threads = 2 waves, 4x4 frags (same scheme as k_qkv).
__global__ __launch_bounds__(128) void k_oproj(const bf16* __restrict__ ob,
    const bf16* __restrict__ wob, float* __restrict__ po) {
  __shared__ bf16 As[128 * 64];
  __shared__ bf16 Bs[64 * 64];
  const int n0 = blockIdx.x * 64;
  const int m0 = blockIdx.y * 128;
  const int kz = blockIdx.z;
  const int tid = threadIdx.x, l = tid & 63, wid = tid >> 6;
  const int wm = wid * 64;
  const bf16* Ap = ob  + (size_t)m0 * DIM + kz * 1024;
  const bf16* Bp = wob + (size_t)n0 * DIM + kz * 1024;
  PBg<128, 128> pa; PBg<64, 128> pb;
  f32x4 acc[4][4] = {};
  pa.load(Ap, DIM, tid); pb.load(Bp, DIM, tid);
  pa.write(As, tid);     pb.write(Bs, tid);
  __syncthreads();
  constexpr int NT = 16;
  for (int kt = 0; kt < NT; ++kt) {
    if (kt + 1 < NT) { pa.load(Ap + (kt + 1) * 64, DIM, tid); pb.load(Bp + (kt + 1) * 64, DIM, tid); }
    mma_tile<4, 4>(As, Bs, acc, l, wm, 0);
    __syncthreads();
    if (kt + 1 < NT) { pa.write(As, tid); pb.write(Bs, tid); }
    __syncthreads();
  }
  float* P = po + (size_t)kz * 1024 * DIM;
  const int rr = (l >> 4) * 4, cc = l & 15;
  #pragma unroll
  for (int mi = 0; mi < 4; ++mi)
    #pragma unroll
    for (int ni = 0; ni < 4; ++ni)
      #pragma unroll
      for (int r = 0; r < 4; ++r)
        P[(size_t)(m0 + wm + mi * 16 + rr + r) * DIM + n0 + ni * 16 + cc] =
            acc[mi][ni][r];
}

// ============ combine: out = po0 + po1 (fp32) ============
__global__ __launch_bounds__(256) void k_ocomb(const float* __restrict__ po,
                                               float* __restrict__ out) {
  const int i0 = (blockIdx.x * 256 + threadIdx.x) * 4;
  float4 a = *reinterpret_cast<const float4*>(po + i0);
  float4 b = *reinterpret_cast<const float4*>(po + 1024 * DIM + i0);
  float4 o = {a.x + b.x, a.y + b.y, a.z + b.z, a.w + b.w};
  *reinterpret_cast<float4*>(out + i0) = o;
}

extern "C" void kernel_launch(void* const* d_in, const int* in_sizes, int n_in,
                              void* d_out, int out_size, void* d_ws, size_t ws_size,
                              hipStream_t stream) {
  const float* x      = (const float*)d_in[0];
  // d_in[1] = mask (unused by the reference forward)
  const float* kcache = (const float*)d_in[2];
  const float* vcache = (const float*)d_in[3];
  const float* wq     = (const float*)d_in[4];
  const float* wk     = (const float*)d_in[5];
  const float* wv     = (const float*)d_in[6];
  const float* wo     = (const float*)d_in[7];
  float* out = (float*)d_out;

  char* ws = (char*)d_ws;                       // ws ~1 GB
  bf16*  xb     = (bf16*)(ws + 0);              //  4.19 MB [1024][2048]
  bf16*  wb     = (bf16*)(ws + 4194304);        // 33.55 MB [4*2048][2048]
  bf16*  qb     = (bf16*)(ws + 37748736);       //  4.19 MB
  bf16*  kb     = (bf16*)(ws + 41943040);       //  4.19 MB
  bf16*  vb     = (bf16*)(ws + 46137344);       //  4.19 MB
  float* scores = (float*)(ws + 50331648);      // 17.30 MB [1024][4224]
  bf16*  attnb  = (bf16*)(ws + 67633152);       //  8.65 MB
  bf16*  obuf   = (bf16*)(ws + 76283904);       //  4.19 MB
  float* pp     = scores;                       // reuse scores region for partials
  bf16*  wob    = wb + (size_t)3 * DIM * DIM;

  k_cvt<<<dim3(2048, 5), 256, 0, stream>>>(x, wq, wk, wv, wo, xb, wb);
  k_qkv<<<dim3(96, 8), 128, 0, stream>>>(xb, wb, qb, kb, vb);
  k_scores<<<dim3(66, 8), 256, 0, stream>>>(qb, kb, kcache, scores);
  k_softmax<<<dim3(1024), 256, 0, stream>>>(scores, attnb);
  k_pv<<<dim3(32, 8, 2), 256, 0, stream>>>(attnb, vcache, vb, pp);
  k_pvcomb<<<dim3(2048), 256, 0, stream>>>(pp, obuf);
  k_oproj<<<dim3(32, 8, 2), 128, 0, stream>>>(obuf, wob, pp);
  k_ocomb<<<dim3(2048), 256, 0, stream>>>(pp, out);
}